// Round 1
// baseline (254.483 us; speedup 1.0000x reference)
//
#include <hip/hip_runtime.h>

#define TB 256

typedef __bf16 bf16x8 __attribute__((ext_vector_type(8)));
typedef float f32x4 __attribute__((ext_vector_type(4)));

__device__ __forceinline__ unsigned pack2bf(float a, float b) {
  unsigned ua = __float_as_uint(a), ub = __float_as_uint(b);
  ua = (ua + 0x7fffu + ((ua >> 16) & 1u)) >> 16;   // RNE f32->bf16
  ub = (ub + 0x7fffu + ((ub >> 16) & 1u)) >> 16;
  return ua | (ub << 16);
}

// One block = 2 b  x  2 p  = 128x128 score tile = 4 (b,p) pairs.
__global__ __launch_bounds__(TB) void dpr_fused(
    const float* __restrict__ q_emb,      // [64,64,768]
    const float* __restrict__ p_emb,      // [128,64,768]
    const void* __restrict__ q_mask_raw,  // [64,64] bool (u8 or i32, sniffed)
    const void* __restrict__ p_mask_raw,  // [128,64]
    const float* __restrict__ alpha_raw,
    const float* __restrict__ beta_raw,
    float* __restrict__ out)              // [64,128]
{
  const int H = 768;
  __shared__ __align__(16) unsigned short Al[128 * 64]; // bf16 bits, swizzled
  __shared__ __align__(16) unsigned short Bl[128 * 64];
  __shared__ float S[4096];
  __shared__ unsigned hist[256];
  __shared__ float glist[64];
  __shared__ unsigned listCnt;
  __shared__ unsigned long long qbits[2], pbits[2];
  __shared__ int nqs[2], nps[2];
  __shared__ float redf[12];
  __shared__ int redi[8];
  __shared__ int selB_s, R_s, c_s;
  __shared__ float t_s, tsum_s, mn_s, mx_s;

  const int tid = threadIdx.x;
  const int lane = tid & 63;
  const int wid = tid >> 6;
  const int bid = blockIdx.x;
  const int blockB = bid >> 6;   // 0..31
  const int blockP = bid & 63;   // 0..63

  // ---- mask dtype sniff (uniform, deterministic) ----
  bool m32 = true;
  {
    const unsigned* qm32 = (const unsigned*)q_mask_raw;
    #pragma unroll
    for (int i = 0; i < 8; ++i) m32 = m32 && (qm32[i] <= 1u);
  }
  {
    if (wid < 2) {
      int b = blockB * 2 + wid;
      bool v = m32 ? (((const int*)q_mask_raw)[b * 64 + lane] != 0)
                   : (((const unsigned char*)q_mask_raw)[b * 64 + lane] != 0);
      unsigned long long m = __ballot(v);
      if (lane == 0) { qbits[wid] = m; nqs[wid] = __popcll(m); }
    } else {
      int p = blockP * 2 + (wid - 2);
      bool v = m32 ? (((const int*)p_mask_raw)[p * 64 + lane] != 0)
                   : (((const unsigned char*)p_mask_raw)[p * 64 + lane] != 0);
      unsigned long long m = __ballot(v);
      if (lane == 0) { pbits[wid - 2] = m; nps[wid - 2] = __popcll(m); }
    }
  }

  // ---- GEMM: 128x128 tile, 4 waves, each wave one 64x64 pair-quadrant ----
  const int lr = lane & 15, lg = lane >> 4;
  const int wr = wid >> 1, wc = wid & 1;
  f32x4 acc[4][4];
  #pragma unroll
  for (int m = 0; m < 4; ++m)
    #pragma unroll
    for (int n = 0; n < 4; ++n)
      acc[m][n] = f32x4{0.f, 0.f, 0.f, 0.f};

  const float* Abase = q_emb + (size_t)(blockB * 128) * H;
  const float* Bbase = p_emb + (size_t)(blockP * 128) * H;

  for (int kt = 0; kt < 12; ++kt) {           // K=768, KC=64
    const int k0 = kt * 64;
    #pragma unroll
    for (int it = 0; it < 4; ++it) {          // 1024 float8-groups per tile
      int g = tid + 256 * it;
      int row = g >> 3;
      int col = (g & 7) * 8;
      int off = (row * 128 + col * 2) ^ ((row & 7) << 4);  // XOR swizzle
      const float4* sA = (const float4*)(Abase + row * H + k0 + col);
      float4 a0 = sA[0], a1 = sA[1];
      uint4 w;
      w.x = pack2bf(a0.x, a0.y); w.y = pack2bf(a0.z, a0.w);
      w.z = pack2bf(a1.x, a1.y); w.w = pack2bf(a1.z, a1.w);
      *(uint4*)((char*)Al + off) = w;
      const float4* sB = (const float4*)(Bbase + row * H + k0 + col);
      float4 b0 = sB[0], b1 = sB[1];
      w.x = pack2bf(b0.x, b0.y); w.y = pack2bf(b0.z, b0.w);
      w.z = pack2bf(b1.x, b1.y); w.w = pack2bf(b1.z, b1.w);
      *(uint4*)((char*)Bl + off) = w;
    }
    __syncthreads();
    #pragma unroll
    for (int ks = 0; ks < 2; ++ks) {
      bf16x8 af[4], bfr[4];
      #pragma unroll
      for (int m = 0; m < 4; ++m) {
        int row = wr * 64 + m * 16 + lr;
        int off = (row * 128 + ks * 64 + lg * 16) ^ ((row & 7) << 4);
        af[m] = *(const bf16x8*)((const char*)Al + off);
      }
      #pragma unroll
      for (int n = 0; n < 4; ++n) {
        int row = wc * 64 + n * 16 + lr;
        int off = (row * 128 + ks * 64 + lg * 16) ^ ((row & 7) << 4);
        bfr[n] = *(const bf16x8*)((const char*)Bl + off);
      }
      #pragma unroll
      for (int m = 0; m < 4; ++m)
        #pragma unroll
        for (int n = 0; n < 4; ++n)
          acc[m][n] = __builtin_amdgcn_mfma_f32_16x16x32_bf16(af[m], bfr[n], acc[m][n], 0, 0, 0);
    }
    __syncthreads();
  }

  const float alpha = log1pf(expf(alpha_raw[0]));
  const float beta  = log1pf(expf(beta_raw[0]));

  float res0 = 0.f, res1 = 0.f;  // meaningful on tid 0 only

  for (int pr = 0; pr < 4; ++pr) {
    const int db = pr >> 1, dp = pr & 1;
    if (wid == pr) {  // owner wave (wr==db, wc==dp) dumps its quadrant
      #pragma unroll
      for (int m = 0; m < 4; ++m)
        #pragma unroll
        for (int n = 0; n < 4; ++n)
          #pragma unroll
          for (int j = 0; j < 4; ++j)
            S[(m * 16 + lg * 4 + j) * 64 + (n * 16 + lr)] = acc[m][n][j];
    }
    __syncthreads();

    const unsigned long long qb = qbits[db], pb = pbits[dp];
    const int n_pair = nqs[db] * nps[dp];

    if (n_pair > 0) {
      // cache 16 values/thread; e = tid + 256*it -> i = wid+4*it, j = lane
      float v[16];
      unsigned validm = 0;
      const unsigned pvbit = (unsigned)((pb >> lane) & 1ULL);
      #pragma unroll
      for (int it = 0; it < 16; ++it) {
        v[it] = S[tid + 256 * it];
        unsigned qv = (unsigned)((qb >> (wid + 4 * it)) & 1ULL);
        validm |= (qv & pvbit) << it;
      }
      // masked sum / min / max
      float ts = 0.f, mn = INFINITY, mx = -INFINITY;
      #pragma unroll
      for (int it = 0; it < 16; ++it)
        if ((validm >> it) & 1u) { ts += v[it]; mn = fminf(mn, v[it]); mx = fmaxf(mx, v[it]); }
      #pragma unroll
      for (int off = 32; off > 0; off >>= 1) {
        ts += __shfl_down(ts, off);
        mn = fminf(mn, __shfl_down(mn, off));
        mx = fmaxf(mx, __shfl_down(mx, off));
      }
      if (lane == 0) { redf[wid] = ts; redf[4 + wid] = mn; redf[8 + wid] = mx; }
      __syncthreads();
      if (tid == 0) {
        tsum_s = redf[0] + redf[1] + redf[2] + redf[3];
        mn_s = fminf(fminf(redf[4], redf[5]), fminf(redf[6], redf[7]));
        mx_s = fmaxf(fmaxf(redf[8], redf[9]), fmaxf(redf[10], redf[11]));
      }
      __syncthreads();
      const float vmn = mn_s, vmx = mx_s;

      int ksel = 4 * n_pair / 10; if (ksel < 1) ksel = 1;
      int lsel = 2 * n_pair / 10; if (lsel < 1) lsel = 1;

      #pragma unroll
      for (int sel = 0; sel < 2; ++sel) {
        const float sgn = sel ? -1.0f : 1.0f;   // sel 1: k-th largest of -v
        const int kk = sel ? lsel : ksel;
        float lo = sel ? -vmx : vmn;
        float hi = sel ? -vmn : vmx;
        unsigned alive = validm;
        int R = kk;
        float tval = 0.0f;
        bool haveT = false;
        for (int L = 0; L < 8; ++L) {
          if (!(hi > lo)) { tval = lo; haveT = true; break; }  // degenerate: all equal
          hist[tid] = 0;
          __syncthreads();
          const float scale = 255.0f / (hi - lo);
          unsigned char mybin[16];
          #pragma unroll
          for (int it = 0; it < 16; ++it) {
            mybin[it] = 255;
            if ((alive >> it) & 1u) {
              int bb = (int)((sgn * v[it] - lo) * scale);
              bb = bb < 0 ? 0 : (bb > 255 ? 255 : bb);
              mybin[it] = (unsigned char)bb;
              atomicAdd(&hist[bb], 1u);
            }
          }
          __syncthreads();
          if (wid == 0) {  // descending scan: find bin holding rank R
            unsigned hh[4];
            #pragma unroll
            for (int i = 0; i < 4; ++i) hh[i] = hist[lane * 4 + i];
            unsigned lsum = hh[0] + hh[1] + hh[2] + hh[3];
            unsigned suf = lsum;
            #pragma unroll
            for (int off = 1; off < 64; off <<= 1) {
              unsigned o = __shfl_down(suf, off);
              if (lane + off < 64) suf += o;
            }
            unsigned above = suf - lsum;   // count in bins of higher lanes
            if ((unsigned)R > above && (unsigned)R <= suf) {
              unsigned a = above;
              #pragma unroll
              for (int i = 3; i >= 0; --i) {
                if ((unsigned)R <= a + hh[i]) {
                  selB_s = lane * 4 + i; R_s = R - (int)a; c_s = (int)hh[i];
                  break;
                }
                a += hh[i];
              }
            }
          }
          __syncthreads();
          const int Bsel = selB_s;
          const int c = c_s;
          R = R_s;
          unsigned na = 0;
          #pragma unroll
          for (int it = 0; it < 16; ++it)
            if (((alive >> it) & 1u) && mybin[it] == (unsigned char)Bsel) na |= 1u << it;
          alive = na;
          const float wdt = (hi - lo) * (1.0f / 255.0f);
          hi = lo + wdt * (float)(Bsel + 1);
          lo = lo + wdt * (float)Bsel;
          if (c <= 64) break;
        }
        if (!haveT) {
          if (tid == 0) listCnt = 0;
          __syncthreads();
          #pragma unroll
          for (int it = 0; it < 16; ++it)
            if ((alive >> it) & 1u) {
              unsigned pos = atomicAdd(&listCnt, 1u);
              if (pos < 64) glist[pos] = sgn * v[it];
            }
          __syncthreads();
          int cc = (int)listCnt; if (cc > 64) cc = 64;
          if (R > cc) R = cc;
          if (wid == 0) {  // exact rank among <=64 candidates
            float myv = (lane < cc) ? glist[lane] : 0.0f;
            int cg = 0, ce = 0;
            for (int q2 = 0; q2 < cc; ++q2) {
              float o = glist[q2];
              if (o > myv) cg++;
              if (o == myv) ce++;
            }
            if (lane < cc && cg < R && R <= cg + ce) t_s = myv;  // same value if ties
          }
          __syncthreads();
          tval = t_s;
        }
        // exact tie-aware sum of top-kk: sum_{x>t} x + t*(kk - cnt_gt)
        float s = 0.f; int cgt = 0;
        #pragma unroll
        for (int it = 0; it < 16; ++it)
          if ((validm >> it) & 1u) {
            float x = sgn * v[it];
            if (x > tval) { s += x; cgt++; }
          }
        #pragma unroll
        for (int off = 32; off > 0; off >>= 1) {
          s += __shfl_down(s, off);
          cgt += __shfl_down(cgt, off);
        }
        if (lane == 0) { redf[wid] = s; redi[wid] = cgt; }
        __syncthreads();
        if (tid == 0) {
          float st = redf[0] + redf[1] + redf[2] + redf[3];
          int ct = redi[0] + redi[1] + redi[2] + redi[3];
          float r = st + tval * (float)(kk - ct);
          if (sel == 0) res0 = r; else res1 = r;
        }
        __syncthreads();
      }

      if (tid == 0) {
        float fn = (float)n_pair;
        float total_mean = tsum_s / fn;
        float top_mean = res0 / (float)ksel;
        // res1 = sum of lsel largest of (-v) = -bottom_sum; relu(-bottom_mean) = max(0, res1/l)
        float bmr = fmaxf(0.0f, res1 / (float)lsel);
        float sim = total_mean + alpha * top_mean - beta * bmr;
        out[(blockB * 2 + db) * 128 + (blockP * 2 + dp)] = sim;
      }
    } else {
      if (tid == 0) out[(blockB * 2 + db) * 128 + (blockP * 2 + dp)] = -1e9f;
    }
    __syncthreads();
  }
}

extern "C" void kernel_launch(void* const* d_in, const int* in_sizes, int n_in,
                              void* d_out, int out_size, void* d_ws, size_t ws_size,
                              hipStream_t stream) {
  (void)in_sizes; (void)n_in; (void)d_ws; (void)ws_size; (void)out_size;
  const float* q_emb = (const float*)d_in[0];
  const float* p_emb = (const float*)d_in[1];
  const void*  q_mask = d_in[2];
  const void*  p_mask = d_in[3];
  const float* alpha_raw = (const float*)d_in[4];
  const float* beta_raw  = (const float*)d_in[5];
  float* out = (float*)d_out;

  dim3 grid(2048);   // 32 (b-pairs) x 64 (p-pairs)
  dim3 block(TB);
  hipLaunchKernelGGL(dpr_fused, grid, block, 0, stream,
                     q_emb, p_emb, q_mask, p_mask, alpha_raw, beta_raw, out);
}